// Round 10
// baseline (8988.660 us; speedup 1.0000x reference)
//
#include <hip/hip_runtime.h>
#include <hip/hip_bf16.h>

// ===== R10: INSTRUMENTATION ROUND =====
// Output-identical to R9. fold1/fold2/fold3/final repeat their work
// reps x (idempotent re-writes), with a volatile zero-offset read per rep
// to defeat hoisting, so each appears in the rocprof top-5 (which is
// otherwise monopolized by ~320us harness fill kernels). Span left
// unscaled (rep re-reads would hit L3 and misreport its HBM-bound time);
// infer span = dur_total - sum(parts)/reps - gaps(from timestamps).

#define B_ 256
#define S_ 512
#define H_ 1024
#define L_ 30
#define CH 64
#define NCHUNK 8

#define REPS_F1 256
#define REPS_F2 64
#define REPS_F3 64
#define REPS_FIN 256

__device__ __forceinline__ void fold_row_T(
    const float* __restrict__ arow, const float* __restrict__ ST,
    size_t sstride, size_t soff, float* acc, int lane) {
  float4 a4[4];
#pragma unroll
  for (int c = 0; c < 4; ++c)
    a4[c] = *(const float4*)(arow + c * 256 + 4 * lane);
  const float* sbase = ST + soff + 4 * lane;
#pragma unroll
  for (int n = 0; n < 30; ++n) {
    const float* srow = sbase + (size_t)n * sstride;
    float s = 0.f;
#pragma unroll
    for (int c = 0; c < 4; ++c) {
      float4 s4 = *(const float4*)(srow + c * 256);
      s += a4[c].x * s4.x + a4[c].y * s4.y + a4[c].z * s4.z + a4[c].w * s4.w;
    }
    acc[n] += s;
  }
}

__device__ __forceinline__ void reduce30_butterfly(float* acc) {
#pragma unroll
  for (int n = 0; n < 30; ++n) {
#pragma unroll
    for (int m = 1; m < 64; m <<= 1) acc[n] += __shfl_xor(acc[n], m);
  }
}

// zero the volatile offset flag (runs first; in-order stream)
__global__ void init_kernel(int* flag) {
  if (threadIdx.x == 0) flag[0] = 0;
}

// ---------------------------------------------------------------------------
// Span partials — UNSCALED, identical to R9.
// ---------------------------------------------------------------------------
__global__ __launch_bounds__(256) void span_kernel(
    const float* __restrict__ x, const int* __restrict__ eidx,
    const float* __restrict__ W_out,
    float* __restrict__ Pspan, float* __restrict__ WoutT) {
  const int b = blockIdx.x;
  const int chunk = blockIdx.y;
  const int role = blockIdx.z;
  const int t = threadIdx.x;

  if (chunk == NCHUNK) {
    if (role == 0 && b < 120) {
      int idx = b * 256 + t;
      if (idx < H_ * L_) {
        int k = idx / L_, n = idx - k * L_;
        WoutT[(size_t)n * H_ + k] = W_out[idx];
      }
    }
    return;
  }

  const int lo = eidx[b * 4 + 2 * role];
  const int hi = eidx[b * 4 + 2 * role + 1];
  int s0 = max(lo, chunk * CH);
  int s1 = min(hi, chunk * CH + CH);
  if (s0 >= s1) return;

  const int col = t * 4;
  const float* base = x + (size_t)b * S_ * H_ + col;
  float x0 = 0.f, y0 = 0.f, z0 = 0.f, w0 = 0.f;
  float x1 = 0.f, y1 = 0.f, z1 = 0.f, w1 = 0.f;
  float x2 = 0.f, y2 = 0.f, z2 = 0.f, w2 = 0.f;
  float x3 = 0.f, y3 = 0.f, z3 = 0.f, w3 = 0.f;
  int s = s0;
  for (; s + 4 <= s1; s += 4) {
    float4 v0 = *(const float4*)(base + (size_t)s * H_);
    float4 v1 = *(const float4*)(base + (size_t)(s + 1) * H_);
    float4 v2 = *(const float4*)(base + (size_t)(s + 2) * H_);
    float4 v3 = *(const float4*)(base + (size_t)(s + 3) * H_);
    x0 += v0.x; y0 += v0.y; z0 += v0.z; w0 += v0.w;
    x1 += v1.x; y1 += v1.y; z1 += v1.z; w1 += v1.w;
    x2 += v2.x; y2 += v2.y; z2 += v2.z; w2 += v2.w;
    x3 += v3.x; y3 += v3.y; z3 += v3.z; w3 += v3.w;
  }
  for (; s < s1; ++s) {
    float4 v = *(const float4*)(base + (size_t)s * H_);
    x0 += v.x; y0 += v.y; z0 += v.z; w0 += v.w;
  }
  float4 o;
  o.x = x0 + x1 + x2 + x3;
  o.y = y0 + y1 + y2 + y3;
  o.z = z0 + z1 + z2 + z3;
  o.w = w0 + w1 + w2 + w3;
  *(float4*)(Pspan + (((size_t)b * 2 + role) * NCHUNK + chunk) * H_ + col) = o;
}

// ---------------------------------------------------------------------------
// fold1 x REPS_F1
// ---------------------------------------------------------------------------
__global__ __launch_bounds__(64) void fold1_kernel(
    const float* __restrict__ W_d2, const float* __restrict__ WoutT,
    float* __restrict__ P1T, const int* flag) {
  const int row = blockIdx.x;
  const int lane = threadIdx.x;
  for (int r = 0; r < REPS_F1; ++r) {
    const int off = *(volatile const int*)flag;
    float acc[30];
#pragma unroll
    for (int n = 0; n < 30; ++n) acc[n] = 0.f;
    fold_row_T(W_d2 + (size_t)row * H_ + off, WoutT + off, H_, 0, acc, lane);
    reduce30_butterfly(acc);
    if (lane == 0) {
#pragma unroll
      for (int n = 0; n < 30; ++n) P1T[(size_t)n * H_ + row] = acc[n];
    }
  }
}

// ---------------------------------------------------------------------------
// fold2 x REPS_F2
// ---------------------------------------------------------------------------
__global__ __launch_bounds__(64) void fold2_kernel(
    const float* __restrict__ W_d1, const float* __restrict__ P1T,
    float* __restrict__ Wd1oT, const int* flag) {
  const int row = blockIdx.x;
  const int lane = threadIdx.x;
  for (int r = 0; r < REPS_F2; ++r) {
    const int off = *(volatile const int*)flag;
    float acc[30];
#pragma unroll
    for (int n = 0; n < 30; ++n) acc[n] = 0.f;
    fold_row_T(W_d1 + (size_t)row * H_ + off, P1T + off, H_, 0, acc, lane);
    reduce30_butterfly(acc);
    if (lane == 0) {
#pragma unroll
      for (int n = 0; n < 30; ++n) Wd1oT[(size_t)n * (3 * H_) + row] = acc[n];
    }
  }
}

// ---------------------------------------------------------------------------
// fold3 x REPS_F3 (+ bias blocks)
// ---------------------------------------------------------------------------
__global__ __launch_bounds__(64) void fold3_kernel(
    const float* __restrict__ W_cls, const float* __restrict__ W_e1,
    const float* __restrict__ W_e2, const float* __restrict__ Wd1oT,
    const float* __restrict__ P1T, const float* __restrict__ WoutT,
    const float* __restrict__ b_cls, const float* __restrict__ b_e1,
    const float* __restrict__ b_e2, const float* __restrict__ b_d1,
    const float* __restrict__ b_d2,
    float* __restrict__ Wf, float* __restrict__ rbias, const int* flag) {
  const int lane = threadIdx.x;
  for (int r = 0; r < REPS_F3; ++r) {
    const int off = *(volatile const int*)flag;
    float acc[30];
#pragma unroll
    for (int n = 0; n < 30; ++n) acc[n] = 0.f;

    if (blockIdx.x < 3 * H_) {
      const int row = blockIdx.x;
      const int z = row >> 10, rr = row & (H_ - 1);
      const float* A = (z == 0) ? W_cls : (z == 1) ? W_e1 : W_e2;
      fold_row_T(A + (size_t)rr * H_ + off, Wd1oT + off, 3 * H_,
                 (size_t)z * H_, acc, lane);
      reduce30_butterfly(acc);
      if (lane == 0) {
#pragma unroll
        for (int n = 0; n < 30; ++n) Wf[(size_t)row * 32 + n] = acc[n];
      }
      continue;
    }
    const int which = blockIdx.x - 3 * H_;
    if (which == 0) {
      float4 bv[12];
#pragma unroll
      for (int c = 0; c < 12; ++c) {
        const float* bsrc = (c < 4) ? (b_cls + c * 256)
                          : (c < 8) ? (b_e1 + (c - 4) * 256)
                                    : (b_e2 + (c - 8) * 256);
        bv[c] = *(const float4*)(bsrc + 4 * lane + off);
      }
      const float* sb = Wd1oT + 4 * lane + off;
#pragma unroll
      for (int n = 0; n < 30; ++n) {
        const float* srow = sb + (size_t)n * (3 * H_);
        float s = 0.f;
#pragma unroll
        for (int c = 0; c < 12; ++c) {
          float4 s4 = *(const float4*)(srow + c * 256);
          s += bv[c].x * s4.x + bv[c].y * s4.y + bv[c].z * s4.z + bv[c].w * s4.w;
        }
        acc[n] += s;
      }
      reduce30_butterfly(acc);
      if (lane == 0) {
#pragma unroll
        for (int n = 0; n < 30; ++n) rbias[n] = acc[n];
      }
    } else if (which == 1) {
      fold_row_T(b_d1 + off, P1T + off, H_, 0, acc, lane);
      reduce30_butterfly(acc);
      if (lane == 0) {
#pragma unroll
        for (int n = 0; n < 30; ++n) rbias[32 + n] = acc[n];
      }
    } else {
      fold_row_T(b_d2 + off, WoutT + off, H_, 0, acc, lane);
      reduce30_butterfly(acc);
      if (lane == 0) {
#pragma unroll
        for (int n = 0; n < 30; ++n) rbias[64 + n] = acc[n];
      }
    }
  }
}

// ---------------------------------------------------------------------------
// final x REPS_FIN
// ---------------------------------------------------------------------------
__global__ __launch_bounds__(256) void final_kernel(
    const float* __restrict__ x, const int* __restrict__ eidx,
    const float* __restrict__ Pspan, const float* __restrict__ Wf,
    const float* __restrict__ b_out, const float* __restrict__ rbias,
    float* __restrict__ out, const int* flag) {
  __shared__ float Ts[3 * H_];
  __shared__ float red[8][30];
  const int b = blockIdx.x;
  const int t = threadIdx.x;
  const int col = t * 4;

  for (int r = 0; r < REPS_FIN; ++r) {
    const int off = *(volatile const int*)flag;
    {
      float4 v = *(const float4*)(x + (size_t)b * S_ * H_ + col + off);
      Ts[col + 0] = tanhf(v.x);
      Ts[col + 1] = tanhf(v.y);
      Ts[col + 2] = tanhf(v.z);
      Ts[col + 3] = tanhf(v.w);
    }
#pragma unroll
    for (int role = 0; role < 2; ++role) {
      const int lo = eidx[b * 4 + 2 * role];
      const int hi = eidx[b * 4 + 2 * role + 1];
      const int c0 = lo >> 6;
      const int c1 = (hi - 1) >> 6;
      float ax = 0.f, ay = 0.f, az = 0.f, aw = 0.f;
      for (int c = c0; c <= c1; ++c) {
        float4 v = *(const float4*)(Pspan + (((size_t)b * 2 + role) * NCHUNK + c) * H_ + col + off);
        ax += v.x; ay += v.y; az += v.z; aw += v.w;
      }
      const float inv = 1.0f / (float)(hi - lo);
      float* Td = Ts + (1 + role) * H_ + col;
      Td[0] = tanhf(ax * inv);
      Td[1] = tanhf(ay * inv);
      Td[2] = tanhf(az * inv);
      Td[3] = tanhf(aw * inv);
    }
    __syncthreads();

    if (t < 240) {
      const int n = t % 30, p = t / 30;
      const int k0 = p * 384;
      float s = 0.f;
#pragma unroll 4
      for (int k = k0; k < k0 + 384; ++k) s += Ts[k] * Wf[(size_t)k * 32 + n + off];
      red[p][n] = s;
    }
    __syncthreads();
    if (t < L_) {
      float s = b_out[t] + rbias[t] + rbias[32 + t] + rbias[64 + t];
#pragma unroll
      for (int p = 0; p < 8; ++p) s += red[p][t];
      out[(size_t)b * L_ + t] = s;
    }
    __syncthreads();
  }
}

extern "C" void kernel_launch(void* const* d_in, const int* in_sizes, int n_in,
                              void* d_out, int out_size, void* d_ws, size_t ws_size,
                              hipStream_t stream) {
  const float* x = (const float*)d_in[0];
  const int* eidx = (const int*)d_in[1];
  const float* W_cls = (const float*)d_in[2];
  const float* b_cls = (const float*)d_in[3];
  const float* W_e1 = (const float*)d_in[4];
  const float* b_e1 = (const float*)d_in[5];
  const float* W_e2 = (const float*)d_in[6];
  const float* b_e2 = (const float*)d_in[7];
  const float* W_d1 = (const float*)d_in[8];
  const float* b_d1 = (const float*)d_in[9];
  const float* W_d2 = (const float*)d_in[10];
  const float* b_d2 = (const float*)d_in[11];
  const float* W_out = (const float*)d_in[12];
  const float* b_out = (const float*)d_in[13];
  float* out = (float*)d_out;

  float* ws = (float*)d_ws;
  float* Pspan = ws;                   // 4,194,304
  float* WoutT = Pspan + 4194304;      // 30,720
  float* P1T   = WoutT + 30720;        // 30,720
  float* Wd1oT = P1T + 30720;          // 92,160
  float* Wf    = Wd1oT + 92160;        // 98,304
  float* rbias = Wf + 98304;           // 96
  int*   flag  = (int*)(rbias + 128);

  init_kernel<<<1, 64, 0, stream>>>(flag);

  span_kernel<<<dim3(B_, NCHUNK + 1, 2), 256, 0, stream>>>(
      x, eidx, W_out, Pspan, WoutT);

  fold1_kernel<<<H_, 64, 0, stream>>>(W_d2, WoutT, P1T, flag);
  fold2_kernel<<<3 * H_, 64, 0, stream>>>(W_d1, P1T, Wd1oT, flag);
  fold3_kernel<<<3 * H_ + 3, 64, 0, stream>>>(
      W_cls, W_e1, W_e2, Wd1oT, P1T, WoutT,
      b_cls, b_e1, b_e2, b_d1, b_d2, Wf, rbias, flag);

  final_kernel<<<B_, 256, 0, stream>>>(x, eidx, Pspan, Wf, b_out, rbias, out, flag);
}